// Round 7
// baseline (2046.603 us; speedup 1.0000x reference)
//
#include <hip/hip_runtime.h>
#include <stdint.h>

// SPINN thin-stack TreeLSTM, MI355X, round 7 = round 6 + FORCED W residency.
// R6 post-mortem: VGPR_Count=128 proved the compiler sank the 200-float W
// slice back to per-step L2 loads (27 TB/s demand ~ 78% of L2 ceiling ->
// L2-BW-bound). R7: W loaded once into wrf[200] and pinned via asm opacity
// barrier ("+v") so remat is impossible; allocator must keep in VGPRs
// (~225 live < 256 cap @ 2 waves/SIMD). Also enforces 1 block/CU in HW.
// Everything else identical to R6 (pairwise fan-in-2 exchange, 3 barriers).

#define D     512
#define HD    128
#define LD    64
#define NTHR  512
#define GPR   328   // gp row stride (floats)

typedef unsigned long long u64t;

__device__ __forceinline__ float sigf(float x){ return 1.0f/(1.0f+__expf(-x)); }
__device__ __forceinline__ float tanh_(float x){ return 1.0f-2.0f/(__expf(2.0f*x)+1.0f); }
__device__ __forceinline__ u64t gld64(const float* p){
  return __hip_atomic_load((const u64t*)p, __ATOMIC_RELAXED, __HIP_MEMORY_SCOPE_AGENT);
}
__device__ __forceinline__ u64t gld64u(const unsigned* p){
  return __hip_atomic_load((const u64t*)p, __ATOMIC_RELAXED, __HIP_MEMORY_SCOPE_AGENT);
}
__device__ __forceinline__ void gst32(float* p, float v){
  __hip_atomic_store(p, v, __ATOMIC_RELAXED, __HIP_MEMORY_SCOPE_AGENT);
}
__device__ __forceinline__ void gsttag(unsigned* p, unsigned v){
  __hip_atomic_store(p, v, __ATOMIC_RELAXED, __HIP_MEMORY_SCOPE_AGENT);
}

__global__ __launch_bounds__(NTHR,2) void spinn_kernel(
    const int* __restrict__ trans, const int* __restrict__ labels,
    const float* __restrict__ emb, const float* __restrict__ W,
    const float* __restrict__ bias, const float* __restrict__ leaf,
    float* __restrict__ out, unsigned* __restrict__ tags,
    float* __restrict__ rec, float* __restrict__ cown)
{
  const int bid = blockIdx.x;
  const int g2 = bid>>1, sl = bid&1, ps = sl^1;
  const int gb0 = g2*2;
  const int tid = threadIdx.x;
  const int kg = tid>>6, lane = tid&63;
  const int cq = lane;

  __shared__ __align__(16) float xs[2][2][320];     // [buf][b][k]
  __shared__ __align__(16) float gpq[16][GPR];      // [(kg*2+b)][col]
  __shared__ float bsl[320];
  __shared__ float lshd[HD];
  __shared__ float clb[2][2][64];
  __shared__ uint8_t mS[D][2];
  __shared__ short liA[D][2];
  __shared__ unsigned short stk_[2][D];

  // --- W slice into registers, PINNED: wrf[0..159]=quad cols, [160..199]=u ---
  float wrf[200];
  {
    const int gq = (cq>>4)*128 + sl*64 + ((cq*4)&63);
    const int gu = 512 + sl*64 + cq;
#pragma unroll
    for (int j=0;j<40;++j){
      int k = kg*40 + j;
      float4 w4 = *(const float4*)(W + (size_t)k*640 + gq);
      wrf[j*4+0]=w4.x; wrf[j*4+1]=w4.y; wrf[j*4+2]=w4.z; wrf[j*4+3]=w4.w;
      wrf[160+j] = W[(size_t)k*640 + gu];
    }
  }
#pragma unroll
  for (int i=0;i<200;++i) asm volatile("" : "+v"(wrf[i]));  // forbid remat/sink

  if (tid < 320){
    int c = tid;
    int gc = (c < 256) ? ((c>>6)*128 + sl*64 + (c&63)) : (512 + sl*64 + (c-256));
    bsl[c] = bias[gc];
  }
  if (tid < HD) lshd[tid] = leaf[tid];
  if (tid < 2){   // precompute (mask, li); ri == t-1 always on a reduce
    int b = tid, p = 0;
    for (int t=0;t<D;++t){
      int m = trans[t*256 + gb0 + b];
      short li = 0;
      if (m) li = (short)stk_[b][p-2];
      mS[t][b] = (uint8_t)m; liA[t][b] = li;
      int np = p - 2*m; stk_[b][np] = (unsigned short)t; p = np+1;
    }
  }
  __syncthreads();

  // --- prefill xs[0]: emb(labels[0]) + leaf (mask(0)==0 by construction) ---
  for (int idx = tid; idx < 640; idx += NTHR){
    int b = (idx >= 320) ? 1 : 0;
    int r = idx - b*320;
    if (r < 64){
      int row = labels[gb0 + b];
      xs[0][b][r] = emb[(size_t)row*LD + r];
    } else {
      xs[0][b][r] = lshd[(r-64)&127];
    }
  }
  __syncthreads();

  auto gemm = [&](int cur){
    float4 a0 = {0.f,0.f,0.f,0.f}, a1 = {0.f,0.f,0.f,0.f};
    float u0 = 0.f, u1 = 0.f;
#pragma unroll
    for (int j4=0;j4<10;++j4){
      int k = kg*40 + j4*4;
      float4 x0 = *(const float4*)&xs[cur][0][k];   // broadcast (all lanes same)
      float4 x1 = *(const float4*)&xs[cur][1][k];
      float xa0[4] = {x0.x,x0.y,x0.z,x0.w};
      float xa1[4] = {x1.x,x1.y,x1.z,x1.w};
#pragma unroll
      for (int jj=0;jj<4;++jj){
        const int j = j4*4+jj;
        float w0 = wrf[j*4+0], w1 = wrf[j*4+1], w2 = wrf[j*4+2], w3 = wrf[j*4+3];
        float wu = wrf[160+j];
        a0.x = __builtin_fmaf(w0, xa0[jj], a0.x);
        a0.y = __builtin_fmaf(w1, xa0[jj], a0.y);
        a0.z = __builtin_fmaf(w2, xa0[jj], a0.z);
        a0.w = __builtin_fmaf(w3, xa0[jj], a0.w);
        a1.x = __builtin_fmaf(w0, xa1[jj], a1.x);
        a1.y = __builtin_fmaf(w1, xa1[jj], a1.y);
        a1.z = __builtin_fmaf(w2, xa1[jj], a1.z);
        a1.w = __builtin_fmaf(w3, xa1[jj], a1.w);
        u0 = __builtin_fmaf(wu, xa0[jj], u0);
        u1 = __builtin_fmaf(wu, xa1[jj], u1);
      }
    }
    *(float4*)&gpq[kg*2+0][cq*4] = a0;
    *(float4*)&gpq[kg*2+1][cq*4] = a1;
    gpq[kg*2+0][256+cq] = u0;
    gpq[kg*2+1][256+cq] = u1;
  };

  float ccprev = 0.f;   // own c[t-1][b][dl] (cell threads only)

  for (int t=0;t<D;++t){
    const int cur = t&1, nxt = cur^1;

    // ---- P1: GEMM_A (waves 0-3) || prefetch t+1 (4-6) || hr spin+load (7) ---
    if (kg < 4){
      gemm(cur);
    } else if (kg == 4){
      if (t+1 < D){
        int b = lane>>5, jj = lane&31;
        int row = labels[(t+1)*256 + gb0 + b];
        float2 ev = *(const float2*)(emb + (size_t)row*LD + jj*2);
        xs[nxt][b][jj*2]   = ev.x;
        xs[nxt][b][jj*2+1] = ev.y;
      }
    } else if (kg == 5){
      if (t+1 < D){
        int b = lane>>5, jj = lane&31;
        int m1 = mS[t+1][b]; int li = liA[t+1][b];
        if (m1){
          if (li <= t-2){
            size_t ro = (((size_t)li*128+g2)*2 + sl)*128 + b*64 + jj*2;
            union{u64t u; float f[2];} h_, c_;
            h_.u = gld64(rec + ro);
            c_.u = gld64(cown + ro);
            xs[nxt][b][64+sl*64+jj*2]   = h_.f[0];
            xs[nxt][b][64+sl*64+jj*2+1] = h_.f[1];
            clb[nxt][b][jj*2]   = c_.f[0];
            clb[nxt][b][jj*2+1] = c_.f[1];
          }
          // li == t-1: cell@t-1 already wrote xs/clb from registers
        } else {
          xs[nxt][b][64+sl*64+jj*2]   = lshd[sl*64+jj*2];
          xs[nxt][b][64+sl*64+jj*2+1] = lshd[sl*64+jj*2+1];
          clb[nxt][b][jj*2]   = lshd[sl*64+jj*2];
          clb[nxt][b][jj*2+1] = lshd[sl*64+jj*2+1];
        }
      }
    } else if (kg == 6){
      if (t+1 < D){
        int b = lane>>5, jj = lane&31;
        int m1 = mS[t+1][b]; int li = liA[t+1][b];
        if (m1){
          if (li <= t-2){
            size_t ro = (((size_t)li*128+g2)*2 + ps)*128 + b*64 + jj*2;
            union{u64t u; float f[2];} h_;
            h_.u = gld64(rec + ro);
            xs[nxt][b][64+ps*64+jj*2]   = h_.f[0];
            xs[nxt][b][64+ps*64+jj*2+1] = h_.f[1];
          }
          // li == t-1: wave 7 writes it from the hr record
        } else {
          xs[nxt][b][64+ps*64+jj*2]    = lshd[ps*64+jj*2];
          xs[nxt][b][64+ps*64+jj*2+1]  = lshd[ps*64+jj*2+1];
          xs[nxt][b][192+ps*64+jj*2]   = lshd[ps*64+jj*2];
          xs[nxt][b][192+ps*64+jj*2+1] = lshd[ps*64+jj*2+1];
        }
      }
    } else { // kg == 7: partner h[t-1]
      if (t > 0){
        const unsigned* tp = tags + (((size_t)(t-1)*128+g2)*2 + ps)*16;
        u64t want = ((u64t)(unsigned)(t-1) << 32) | (unsigned)(t-1);
        int it = 0;
        while (gld64u(tp) != want){
          __builtin_amdgcn_s_sleep(1);
          if (++it > (1<<20)) break;   // safety: hang -> wrong answer
        }
        int b = lane>>5, jj = lane&31;
        size_t ro = (((size_t)(t-1)*128+g2)*2 + ps)*128 + lane*2;
        union{u64t u; float f[2];} h_;
        h_.u = gld64(rec + ro);
        if (mS[t][b]){
          xs[cur][b][192+ps*64+jj*2]   = h_.f[0];
          xs[cur][b][192+ps*64+jj*2+1] = h_.f[1];
        }
        if (t+1 < D && mS[t+1][b] && liA[t+1][b] == t-1){
          xs[nxt][b][64+ps*64+jj*2]   = h_.f[0];
          xs[nxt][b][64+ps*64+jj*2+1] = h_.f[1];
        }
      }
    }
    __syncthreads();

    // ---- P2: GEMM_B (waves 4-7, k in [160,320)) ----
    if (kg >= 4){ gemm(cur); }
    __syncthreads();

    // ---- P3: cell (2 waves) ----
    if (tid < 128){
      const int b = tid>>6, dl = tid&63, gd = sl*64+dl;
      const int m = mS[t][b];
      float s[5];
#pragma unroll
      for (int g=0; g<5; ++g){
        int c = (g<4) ? (g*64+dl) : (256+dl);
        float a = 0.f;
#pragma unroll
        for (int kk=0; kk<8; ++kk) a += gpq[kk*2+b][c];
        s[g] = a + bsl[c];
      }
      float cl_ = m ? clb[cur][b][dl] : lshd[gd];
      float cr_ = m ? ccprev : lshd[gd];            // ri == t-1: own prev c
      float cc = sigf(s[0])*tanh_(s[4]) + sigf(s[1])*cl_ + sigf(s[2])*cr_;
      float hh = sigf(s[3])*tanh_(cc);
      ccprev = cc;
      size_t ro = (((size_t)t*128 + g2)*2 + sl)*128 + b*64 + dl;
      gst32(rec + ro, hh);
      gst32(cown + ro, cc);
      if (t == D-1){
        out[(size_t)(gb0+b)*HD + gd] = cc;
        out[(size_t)256*HD + (size_t)(gb0+b)*HD + gd] = hh;
      } else {
        xs[nxt][b][192+gd] = mS[t+1][b] ? hh : lshd[gd];   // own hr for t+1
      }
      if (t+2 < D && mS[t+2][b] && liA[t+2][b] == t){
        xs[cur][b][64+gd]  = hh;    // own hl for t+2 (li==t case)
        clb[cur][b][dl]    = cc;    // own cl for t+2
      }
      __asm__ volatile("s_waitcnt vmcnt(0)" ::: "memory");  // wave-local drain
      if (dl == 0)
        gsttag(tags + (((size_t)t*128+g2)*2+sl)*16 + b, (unsigned)t);
    }
    __syncthreads();
  }
}

extern "C" void kernel_launch(void* const* d_in, const int* in_sizes, int n_in,
                              void* d_out, int out_size, void* d_ws, size_t ws_size,
                              hipStream_t stream) {
  (void)in_sizes; (void)n_in; (void)out_size; (void)ws_size;
  const int*   trans  = (const int*)d_in[0];
  const int*   labels = (const int*)d_in[1];
  const float* emb    = (const float*)d_in[2];
  const float* W      = (const float*)d_in[3];
  const float* bias   = (const float*)d_in[4];
  const float* leaf   = (const float*)d_in[5];
  float* out = (float*)d_out;

  // ws: [0,8MB) tags (64B per (t,g2,sl); 0xAA poison != any t<512 -> no init)
  //     [8MB,72MB) rec: h records | [72MB,136MB) cown: c records
  uint8_t* ws = (uint8_t*)d_ws;
  unsigned* tags = (unsigned*)ws;
  float* rec  = (float*)(ws + ((size_t)8<<20));
  float* cown = (float*)(ws + ((size_t)72<<20));

  spinn_kernel<<<dim3(256), dim3(NTHR), 0, stream>>>(
      trans, labels, emb, W, bias, leaf, out, tags, rec, cown);
}